// Round 15
// baseline (54.908 us; speedup 1.0000x reference)
//
#include <hip/hip_runtime.h>
#include <math.h>

// GAT aggregator: out = relu( deg>0 ? segment_softmax(leaky(s_src[src]+s_dst[dst])) @ Wh[dst] : Wh )
// N=100000, E=1600000, D=64. edge_src is SORTED.
// wh: bf16 MFMA, W staged once per block in LDS (R14). agg: 8-lane group per node,
// 2-stage double-buffered gather (R9 structure), PLAIN loads/stores (no nt hints).

#define DD 64

typedef __attribute__((ext_vector_type(8))) short bf16x8;
typedef __attribute__((ext_vector_type(4))) float f32x4;

static __device__ __forceinline__ unsigned short f2bf(float x) {
    unsigned int u = __float_as_uint(x);
    u += 0x7fffu + ((u >> 16) & 1u);          // RNE
    return (unsigned short)(u >> 16);
}

static __device__ __forceinline__ bf16x8 cvt8(float4 x0, float4 x1) {
    bf16x8 f;
    f[0] = (short)f2bf(x0.x); f[1] = (short)f2bf(x0.y);
    f[2] = (short)f2bf(x0.z); f[3] = (short)f2bf(x0.w);
    f[4] = (short)f2bf(x1.x); f[5] = (short)f2bf(x1.y);
    f[6] = (short)f2bf(x1.z); f[7] = (short)f2bf(x1.w);
    return f;
}

static __device__ __forceinline__ void fma8(float p, uint4 q, float* acc) {
    acc[0] = fmaf(p, __uint_as_float(q.x << 16),          acc[0]);
    acc[1] = fmaf(p, __uint_as_float(q.x & 0xffff0000u),  acc[1]);
    acc[2] = fmaf(p, __uint_as_float(q.y << 16),          acc[2]);
    acc[3] = fmaf(p, __uint_as_float(q.y & 0xffff0000u),  acc[3]);
    acc[4] = fmaf(p, __uint_as_float(q.z << 16),          acc[4]);
    acc[5] = fmaf(p, __uint_as_float(q.z & 0xffff0000u),  acc[5]);
    acc[6] = fmaf(p, __uint_as_float(q.w << 16),          acc[6]);
    acc[7] = fmaf(p, __uint_as_float(q.w & 0xffff0000u),  acc[7]);
}

// ---------------- Kernel 1: Whb = bf16(h @ W^T) via MFMA; W via LDS ---------------
__global__ __launch_bounds__(256) void wh_kernel(
    const float* __restrict__ h, const float* __restrict__ W,
    const float* __restrict__ a, unsigned short* __restrict__ Whb,
    float* __restrict__ s_src, float* __restrict__ s_dst, int N)
{
    __shared__ unsigned short Wsh[64][64];       // bf16 W, 8KB, staged once per block
    __shared__ unsigned short pack[4][16][72];   // per-wave repack buffer

    int t = threadIdx.x;

    #pragma unroll
    for (int c = 0; c < 4; ++c) {
        int idx = c * 256 + t;                   // float4 index 0..1023
        int row = idx >> 4;
        int c4  = idx & 15;
        float4 v = ((const float4*)W)[idx];
        unsigned short b[4] = {f2bf(v.x), f2bf(v.y), f2bf(v.z), f2bf(v.w)};
        *(uint2*)&Wsh[row][c4 * 4] = *(const uint2*)b;
    }
    __syncthreads();

    int w    = threadIdx.x >> 6;
    int lane = threadIdx.x & 63;
    int lr   = lane & 15;
    int lk   = lane >> 4;
    int m0   = blockIdx.x * 64 + w * 16;
    if (m0 >= N) return;                         // after barrier; wave-uniform

    bf16x8 bfr[4][2];
    #pragma unroll
    for (int tt = 0; tt < 4; ++tt)
        #pragma unroll
        for (int q = 0; q < 2; ++q)
            bfr[tt][q] = *(const bf16x8*)&Wsh[tt * 16 + lr][q * 32 + lk * 8];

    int arow = m0 + lr; if (arow >= N) arow = N - 1;
    const float* hrow = h + (size_t)arow * DD;
    bf16x8 afr[2];
    #pragma unroll
    for (int q = 0; q < 2; ++q) {
        float4 x0 = *(const float4*)(hrow + q * 32 + lk * 8);
        float4 x1 = *(const float4*)(hrow + q * 32 + lk * 8 + 4);
        afr[q] = cvt8(x0, x1);
    }

    f32x4 acc[4];
    #pragma unroll
    for (int tt = 0; tt < 4; ++tt) {
        f32x4 z = {0.f, 0.f, 0.f, 0.f};
        z = __builtin_amdgcn_mfma_f32_16x16x32_bf16(afr[0], bfr[tt][0], z, 0, 0, 0);
        acc[tt] = __builtin_amdgcn_mfma_f32_16x16x32_bf16(afr[1], bfr[tt][1], z, 0, 0, 0);
    }

    float av0[4], av1[4];
    #pragma unroll
    for (int tt = 0; tt < 4; ++tt) {
        av0[tt] = a[tt * 16 + lr];
        av1[tt] = a[DD + tt * 16 + lr];
    }
    #pragma unroll
    for (int r = 0; r < 4; ++r) {
        float ssrc = 0.f, sdst = 0.f;
        #pragma unroll
        for (int tt = 0; tt < 4; ++tt) {
            ssrc = fmaf(acc[tt][r], av0[tt], ssrc);
            sdst = fmaf(acc[tt][r], av1[tt], sdst);
        }
        #pragma unroll
        for (int off = 1; off < 16; off <<= 1) {
            ssrc += __shfl_xor(ssrc, off);
            sdst += __shfl_xor(sdst, off);
        }
        if (lr == 0) {
            int row = m0 + lk * 4 + r;
            if (row < N) { s_src[row] = ssrc; s_dst[row] = sdst; }
        }
    }

    #pragma unroll
    for (int tt = 0; tt < 4; ++tt)
        #pragma unroll
        for (int r = 0; r < 4; ++r)
            pack[w][lk * 4 + r][tt * 16 + lr] = f2bf(acc[tt][r]);

    int prow = lane >> 2;
    int pcol = (lane & 3) * 16;
    int grow = m0 + prow;
    if (grow < N) {
        uint4 v0 = *(const uint4*)&pack[w][prow][pcol];
        uint4 v1 = *(const uint4*)&pack[w][prow][pcol + 8];
        *(uint4*)(Whb + (size_t)grow * DD + pcol)     = v0;
        *(uint4*)(Whb + (size_t)grow * DD + pcol + 8) = v1;
    }
}

// ---------------- Kernel 2: edge-parallel row_ptr boundary scatter -----------------
__global__ __launch_bounds__(256) void rowptr_kernel(
    const int* __restrict__ src, int* __restrict__ row_ptr, int E, int N)
{
    int i = blockIdx.x * 256 + threadIdx.x;
    if (i >= E) return;
    int s   = src[i];
    int nxt = (i + 1 < E) ? src[i + 1] : N;
    if (i == 0)
        for (int n = 0; n <= s; ++n) row_ptr[n] = 0;
    for (int n = s + 1; n <= nxt; ++n) row_ptr[n] = i + 1;
}

// ---------------- Kernel 3: 8-lane group per node; 2-stage double-buffered gather --
__global__ __launch_bounds__(256) void agg_kernel(
    const unsigned short* __restrict__ Whb, const float* __restrict__ s_src,
    const float* __restrict__ s_dst, const int* __restrict__ edge_dst,
    const int* __restrict__ row_ptr, float* __restrict__ out, int N)
{
    int tid  = blockIdx.x * 256 + threadIdx.x;
    int node = tid >> 3;                         // 8 lanes per node
    int c8   = threadIdx.x & 7;                  // this lane owns feats c8*8..c8*8+7
    if (node >= N) return;

    int lo = row_ptr[node], hi = row_ptr[node + 1];
    size_t obase = (size_t)node * DD;

    if (lo == hi) {                              // no outgoing edges: relu(Wh row)
        uint4 q = *(const uint4*)(Whb + obase + c8 * 8);
        float v[8] = {};
        fma8(1.f, q, v);
        float4 o0 = make_float4(fmaxf(v[0], 0.f), fmaxf(v[1], 0.f),
                                fmaxf(v[2], 0.f), fmaxf(v[3], 0.f));
        float4 o1 = make_float4(fmaxf(v[4], 0.f), fmaxf(v[5], 0.f),
                                fmaxf(v[6], 0.f), fmaxf(v[7], 0.f));
        ((float4*)(out + obase))[c8 * 2]     = o0;
        ((float4*)(out + obase))[c8 * 2 + 1] = o1;
        return;
    }

    float ss    = s_src[node];
    float denom = 0.f;                           // identical in all 8 lanes
    float acc[8] = {};

    uint4 qA[4], qB[4];
    float pA[4], pB[4];

    auto LOADX = [&](uint4* q, float* p, int base) {
        #pragma unroll
        for (int k = 0; k < 4; ++k) {
            int ii = (base + k < hi) ? base + k : hi - 1;   // clamp: dup loads, p=0
            int d  = edge_dst[ii];
            float sd = s_dst[d];
            q[k] = *(const uint4*)(Whb + (size_t)d * DD + c8 * 8);
            float x = ss + sd;
            x = x > 0.f ? x : 0.2f * x;          // leaky_relu(0.2)
            p[k] = (base + k < hi) ? __expf(x) : 0.f;
        }
    };
    auto CONS = [&](uint4* q, float* p) {
        denom += (p[0] + p[1]) + (p[2] + p[3]);
        fma8(p[0], q[0], acc);
        fma8(p[1], q[1], acc);
        fma8(p[2], q[2], acc);
        fma8(p[3], q[3], acc);
    };

    int nb = (hi - lo + 3) >> 2;                 // 4-edge blocks
    LOADX(qA, pA, lo);
    int bi = 1;
    for (; bi + 1 < nb; bi += 2) {               // keep next block's loads in flight
        LOADX(qB, pB, lo + bi * 4);
        CONS(qA, pA);
        LOADX(qA, pA, lo + (bi + 1) * 4);
        CONS(qB, pB);
    }
    if (bi < nb) {
        LOADX(qB, pB, lo + bi * 4);
        CONS(qA, pA);
        CONS(qB, pB);
    } else {
        CONS(qA, pA);
    }

    float inv = 1.f / denom;
    float4 o0 = make_float4(fmaxf(acc[0] * inv, 0.f), fmaxf(acc[1] * inv, 0.f),
                            fmaxf(acc[2] * inv, 0.f), fmaxf(acc[3] * inv, 0.f));
    float4 o1 = make_float4(fmaxf(acc[4] * inv, 0.f), fmaxf(acc[5] * inv, 0.f),
                            fmaxf(acc[6] * inv, 0.f), fmaxf(acc[7] * inv, 0.f));
    ((float4*)(out + obase))[c8 * 2]     = o0;
    ((float4*)(out + obase))[c8 * 2 + 1] = o1;
}

// ---------------- launch ----------------
extern "C" void kernel_launch(void* const* d_in, const int* in_sizes, int n_in,
                              void* d_out, int out_size, void* d_ws, size_t ws_size,
                              hipStream_t stream)
{
    const float* h    = (const float*)d_in[0];
    const float* W    = (const float*)d_in[1];
    const float* a    = (const float*)d_in[2];
    const int*   esrc = (const int*)d_in[3];
    const int*   edst = (const int*)d_in[4];

    int N = in_sizes[0] / DD;
    int E = in_sizes[3];
    float* out = (float*)d_out;

    // ws layout: Whb (N*64 bf16) | s_src (N f32) | s_dst (N f32) | row_ptr (N+1)
    unsigned short* Whb = (unsigned short*)d_ws;          // 12.8 MB
    float* s_src   = (float*)(Whb + (size_t)N * DD);      // 0.4 MB
    float* s_dst   = s_src + N;                           // 0.4 MB
    int*   row_ptr = (int*)(s_dst + N);                   // 0.4 MB

    wh_kernel<<<(N + 63) / 64, 256, 0, stream>>>(h, W, a, Whb, s_src, s_dst, N);
    rowptr_kernel<<<(E + 255) / 256, 256, 0, stream>>>(esrc, row_ptr, E, N);
    int aggThreads = N * 8;
    agg_kernel<<<(aggThreads + 255) / 256, 256, 0, stream>>>(Whb, s_src, s_dst, edst, row_ptr, out, N);
}

// Round 16
// 50.086 us; speedup vs baseline: 1.0963x; 1.0963x over previous
//
#include <hip/hip_runtime.h>
#include <math.h>

// GAT aggregator: out = relu( deg>0 ? segment_softmax(leaky(s_src[src]+s_dst[dst])) @ Wh[dst] : Wh )
// N=100000, E=1600000, D=64. edge_src is SORTED.
// prep: fused {bf16-MFMA Wh + scores} (blocks < whBlocks) and {rowptr scatter} (rest).
// agg: R14 best — one 8-lane group per node, 4-wide ILP, bf16 rows (1 line/row).

#define DD 64

typedef __attribute__((ext_vector_type(8))) short bf16x8;
typedef __attribute__((ext_vector_type(4))) float f32x4;

static __device__ __forceinline__ unsigned short f2bf(float x) {
    unsigned int u = __float_as_uint(x);
    u += 0x7fffu + ((u >> 16) & 1u);          // RNE
    return (unsigned short)(u >> 16);
}

static __device__ __forceinline__ bf16x8 cvt8(float4 x0, float4 x1) {
    bf16x8 f;
    f[0] = (short)f2bf(x0.x); f[1] = (short)f2bf(x0.y);
    f[2] = (short)f2bf(x0.z); f[3] = (short)f2bf(x0.w);
    f[4] = (short)f2bf(x1.x); f[5] = (short)f2bf(x1.y);
    f[6] = (short)f2bf(x1.z); f[7] = (short)f2bf(x1.w);
    return f;
}

static __device__ __forceinline__ void fma8(float p, uint4 q, float* acc) {
    acc[0] = fmaf(p, __uint_as_float(q.x << 16),          acc[0]);
    acc[1] = fmaf(p, __uint_as_float(q.x & 0xffff0000u),  acc[1]);
    acc[2] = fmaf(p, __uint_as_float(q.y << 16),          acc[2]);
    acc[3] = fmaf(p, __uint_as_float(q.y & 0xffff0000u),  acc[3]);
    acc[4] = fmaf(p, __uint_as_float(q.z << 16),          acc[4]);
    acc[5] = fmaf(p, __uint_as_float(q.z & 0xffff0000u),  acc[5]);
    acc[6] = fmaf(p, __uint_as_float(q.w << 16),          acc[6]);
    acc[7] = fmaf(p, __uint_as_float(q.w & 0xffff0000u),  acc[7]);
}

// ---------------- Kernel 1 (fused): wh (blocks < whBlocks) | rowptr (rest) ---------
__global__ __launch_bounds__(256) void prep_kernel(
    const float* __restrict__ h, const float* __restrict__ W,
    const float* __restrict__ a, const int* __restrict__ esrc,
    unsigned short* __restrict__ Whb, float* __restrict__ s_src,
    float* __restrict__ s_dst, int* __restrict__ row_ptr,
    int N, int E, int whBlocks)
{
    __shared__ unsigned short Wsh[64][64];       // bf16 W, 8KB (wh path only)
    __shared__ unsigned short pack[4][16][72];   // per-wave repack buffer

    if ((int)blockIdx.x >= whBlocks) {
        // ---- rowptr path: edge-parallel boundary scatter (no barriers) ----
        int i = ((int)blockIdx.x - whBlocks) * 256 + threadIdx.x;
        if (i >= E) return;
        int s   = esrc[i];
        int nxt = (i + 1 < E) ? esrc[i + 1] : N;
        if (i == 0)
            for (int n = 0; n <= s; ++n) row_ptr[n] = 0;
        for (int n = s + 1; n <= nxt; ++n) row_ptr[n] = i + 1;
        return;
    }

    // ---- wh path ----
    int t = threadIdx.x;

    #pragma unroll
    for (int c = 0; c < 4; ++c) {
        int idx = c * 256 + t;                   // float4 index 0..1023
        int row = idx >> 4;
        int c4  = idx & 15;
        float4 v = ((const float4*)W)[idx];
        unsigned short b[4] = {f2bf(v.x), f2bf(v.y), f2bf(v.z), f2bf(v.w)};
        *(uint2*)&Wsh[row][c4 * 4] = *(const uint2*)b;
    }
    __syncthreads();

    int w    = threadIdx.x >> 6;
    int lane = threadIdx.x & 63;
    int lr   = lane & 15;
    int lk   = lane >> 4;
    int m0   = blockIdx.x * 64 + w * 16;
    if (m0 >= N) return;                         // after barrier; wave-uniform

    bf16x8 bfr[4][2];
    #pragma unroll
    for (int tt = 0; tt < 4; ++tt)
        #pragma unroll
        for (int q = 0; q < 2; ++q)
            bfr[tt][q] = *(const bf16x8*)&Wsh[tt * 16 + lr][q * 32 + lk * 8];

    int arow = m0 + lr; if (arow >= N) arow = N - 1;
    const float* hrow = h + (size_t)arow * DD;
    bf16x8 afr[2];
    #pragma unroll
    for (int q = 0; q < 2; ++q) {
        float4 x0 = *(const float4*)(hrow + q * 32 + lk * 8);
        float4 x1 = *(const float4*)(hrow + q * 32 + lk * 8 + 4);
        afr[q] = cvt8(x0, x1);
    }

    f32x4 acc[4];
    #pragma unroll
    for (int tt = 0; tt < 4; ++tt) {
        f32x4 z = {0.f, 0.f, 0.f, 0.f};
        z = __builtin_amdgcn_mfma_f32_16x16x32_bf16(afr[0], bfr[tt][0], z, 0, 0, 0);
        acc[tt] = __builtin_amdgcn_mfma_f32_16x16x32_bf16(afr[1], bfr[tt][1], z, 0, 0, 0);
    }

    float av0[4], av1[4];
    #pragma unroll
    for (int tt = 0; tt < 4; ++tt) {
        av0[tt] = a[tt * 16 + lr];
        av1[tt] = a[DD + tt * 16 + lr];
    }
    #pragma unroll
    for (int r = 0; r < 4; ++r) {
        float ssrc = 0.f, sdst = 0.f;
        #pragma unroll
        for (int tt = 0; tt < 4; ++tt) {
            ssrc = fmaf(acc[tt][r], av0[tt], ssrc);
            sdst = fmaf(acc[tt][r], av1[tt], sdst);
        }
        #pragma unroll
        for (int off = 1; off < 16; off <<= 1) {
            ssrc += __shfl_xor(ssrc, off);
            sdst += __shfl_xor(sdst, off);
        }
        if (lr == 0) {
            int row = m0 + lk * 4 + r;
            if (row < N) { s_src[row] = ssrc; s_dst[row] = sdst; }
        }
    }

    #pragma unroll
    for (int tt = 0; tt < 4; ++tt)
        #pragma unroll
        for (int r = 0; r < 4; ++r)
            pack[w][lk * 4 + r][tt * 16 + lr] = f2bf(acc[tt][r]);

    int prow = lane >> 2;
    int pcol = (lane & 3) * 16;
    int grow = m0 + prow;
    if (grow < N) {
        uint4 v0 = *(const uint4*)&pack[w][prow][pcol];
        uint4 v1 = *(const uint4*)&pack[w][prow][pcol + 8];
        *(uint4*)(Whb + (size_t)grow * DD + pcol)     = v0;
        *(uint4*)(Whb + (size_t)grow * DD + pcol + 8) = v1;
    }
}

// ---------------- Kernel 2: one 8-lane group per node; fused, 4-wide ILP -----------
__global__ __launch_bounds__(256) void agg_kernel(
    const unsigned short* __restrict__ Whb, const float* __restrict__ s_src,
    const float* __restrict__ s_dst, const int* __restrict__ edge_dst,
    const int* __restrict__ row_ptr, float* __restrict__ out, int N)
{
    int tid  = blockIdx.x * 256 + threadIdx.x;
    int node = tid >> 3;                         // 8 lanes per node
    int c8   = threadIdx.x & 7;                  // this lane owns feats c8*8..c8*8+7
    if (node >= N) return;

    int lo = row_ptr[node], hi = row_ptr[node + 1];
    size_t obase = (size_t)node * DD;

    if (lo == hi) {                              // no outgoing edges: relu(Wh row)
        uint4 q = *(const uint4*)(Whb + obase + c8 * 8);
        float v[8] = {};
        fma8(1.f, q, v);
        float4 o0 = make_float4(fmaxf(v[0], 0.f), fmaxf(v[1], 0.f),
                                fmaxf(v[2], 0.f), fmaxf(v[3], 0.f));
        float4 o1 = make_float4(fmaxf(v[4], 0.f), fmaxf(v[5], 0.f),
                                fmaxf(v[6], 0.f), fmaxf(v[7], 0.f));
        ((float4*)(out + obase))[c8 * 2]     = o0;
        ((float4*)(out + obase))[c8 * 2 + 1] = o1;
        return;
    }

    float ss    = s_src[node];
    float denom = 0.f;                           // identical in all 8 lanes
    float acc[8] = {};

    for (int e = lo; e < hi; e += 4) {           // 4 independent row-gathers in flight
        int i1 = (e + 1 < hi) ? e + 1 : hi - 1;  // clamp: dup loads, p forced 0
        int i2 = (e + 2 < hi) ? e + 2 : hi - 1;
        int i3 = (e + 3 < hi) ? e + 3 : hi - 1;
        int d0 = edge_dst[e],  d1 = edge_dst[i1];
        int d2 = edge_dst[i2], d3 = edge_dst[i3];
        float t0 = s_dst[d0], t1 = s_dst[d1], t2 = s_dst[d2], t3 = s_dst[d3];
        uint4 q0 = *(const uint4*)(Whb + (size_t)d0 * DD + c8 * 8);
        uint4 q1 = *(const uint4*)(Whb + (size_t)d1 * DD + c8 * 8);
        uint4 q2 = *(const uint4*)(Whb + (size_t)d2 * DD + c8 * 8);
        uint4 q3 = *(const uint4*)(Whb + (size_t)d3 * DD + c8 * 8);
        float x0 = ss + t0, x1 = ss + t1, x2 = ss + t2, x3 = ss + t3;
        x0 = x0 > 0.f ? x0 : 0.2f * x0;          // leaky_relu(0.2)
        x1 = x1 > 0.f ? x1 : 0.2f * x1;
        x2 = x2 > 0.f ? x2 : 0.2f * x2;
        x3 = x3 > 0.f ? x3 : 0.2f * x3;
        float p0 = __expf(x0);                   // |e| small -> skip max-shift
        float p1 = (e + 1 < hi) ? __expf(x1) : 0.f;
        float p2 = (e + 2 < hi) ? __expf(x2) : 0.f;
        float p3 = (e + 3 < hi) ? __expf(x3) : 0.f;
        denom += (p0 + p1) + (p2 + p3);
        fma8(p0, q0, acc);
        fma8(p1, q1, acc);
        fma8(p2, q2, acc);
        fma8(p3, q3, acc);
    }

    float inv = 1.f / denom;
    float4 o0 = make_float4(fmaxf(acc[0] * inv, 0.f), fmaxf(acc[1] * inv, 0.f),
                            fmaxf(acc[2] * inv, 0.f), fmaxf(acc[3] * inv, 0.f));
    float4 o1 = make_float4(fmaxf(acc[4] * inv, 0.f), fmaxf(acc[5] * inv, 0.f),
                            fmaxf(acc[6] * inv, 0.f), fmaxf(acc[7] * inv, 0.f));
    ((float4*)(out + obase))[c8 * 2]     = o0;
    ((float4*)(out + obase))[c8 * 2 + 1] = o1;
}

// ---------------- launch ----------------
extern "C" void kernel_launch(void* const* d_in, const int* in_sizes, int n_in,
                              void* d_out, int out_size, void* d_ws, size_t ws_size,
                              hipStream_t stream)
{
    const float* h    = (const float*)d_in[0];
    const float* W    = (const float*)d_in[1];
    const float* a    = (const float*)d_in[2];
    const int*   esrc = (const int*)d_in[3];
    const int*   edst = (const int*)d_in[4];

    int N = in_sizes[0] / DD;
    int E = in_sizes[3];
    float* out = (float*)d_out;

    // ws layout: Whb (N*64 bf16) | s_src (N f32) | s_dst (N f32) | row_ptr (N+1)
    unsigned short* Whb = (unsigned short*)d_ws;          // 12.8 MB
    float* s_src   = (float*)(Whb + (size_t)N * DD);      // 0.4 MB
    float* s_dst   = s_src + N;                           // 0.4 MB
    int*   row_ptr = (int*)(s_dst + N);                   // 0.4 MB

    int whBlocks  = (N + 63) / 64;
    int rowBlocks = (E + 255) / 256;
    prep_kernel<<<whBlocks + rowBlocks, 256, 0, stream>>>(
        h, W, a, esrc, Whb, s_src, s_dst, row_ptr, N, E, whBlocks);
    int aggThreads = N * 8;
    agg_kernel<<<(aggThreads + 255) / 256, 256, 0, stream>>>(Whb, s_src, s_dst, edst, row_ptr, out, N);
}